// Round 1
// baseline (439.810 us; speedup 1.0000x reference)
//
#include <hip/hip_runtime.h>
#include <hip/hip_bf16.h>

#define BATCH 16384
#define DIM   64
#define NNB   32
#define INDIM 4096          // 2 * NNB * DIM
#define BR    64            // batch rows per block
#define KC    128           // k-chunk = one neighbor (rel 64 + tail 64)

typedef __attribute__((ext_vector_type(8))) short          s16x8;
typedef __attribute__((ext_vector_type(4))) float          f32x4;
typedef __attribute__((ext_vector_type(4))) unsigned int   u32x4;
typedef __attribute__((ext_vector_type(4))) unsigned short u16x4;

__device__ __forceinline__ float bf2f(unsigned short u) {
    union { unsigned int i; float f; } v;
    v.i = ((unsigned int)u) << 16;
    return v.f;
}

template<bool FP32>
__device__ __forceinline__ float ldT(const void* p, size_t i) {
    if constexpr (FP32) return ((const float*)p)[i];
    else                return bf2f(((const unsigned short*)p)[i]);
}

// ws layout: [0:8) double loss accumulator, [8:12) int dtype flag (1=fp32, 0=bf16)
__global__ void kgnn_probe(const unsigned int* __restrict__ lab, int* __restrict__ flag) {
    if (threadIdx.x == 0) {
        int ok = 1;
        for (int i = 0; i < 32; ++i) {
            unsigned int w = lab[i];
            if (!(w == 0u || w == 0x3F800000u)) ok = 0;   // exactly 0.0f or 1.0f
        }
        *flag = ok;   // all-clean fp32 words -> fp32 problem; else bf16
    }
}

// MFMA GEMM kernel. Block = 512 threads = 8 waves, BR=64 batch rows/block.
// Wave w: row-tile rt = w&3 (16 rows), dim-half dh = w>>2 (32 of 64 dims).
// K-loop chunked by neighbor: chunk n covers t_r[:, n*128 .. n*128+128)
// (= rel row 64 elems ++ tail row 64 elems). LDS tiles are [row][128] bf16,
// XOR-swizzled (byte ^= (row&7)<<4) for conflict-free ds_read_b128 frags.
// fp32 problems: split each f32 into bf16 hi+lo, 3 MFMA passes (hi*hi+hi*lo+lo*hi).
template<bool FP32>
__global__ __launch_bounds__(512, 2) void kgnn_mfma(
    const int* __restrict__ users, const int* __restrict__ items,
    const void* __restrict__ label_, const int* __restrict__ nrel,
    const int* __restrict__ ntail,  const void* __restrict__ uemb_,
    const void* __restrict__ eemb_, const void* __restrict__ remb_,
    const void* __restrict__ W_,    const void* __restrict__ b_,
    double* __restrict__ acc, const int* __restrict__ flag, const int force)
{
    if (force < 0 && *flag != (FP32 ? 1 : 0)) return;  // fallback mode: wrong dtype exits

    constexpr int TB = FP32 ? 32768 : 16384;   // tile bytes: [hi 16K][lo 16K] for fp32
    constexpr int LO = 16384;
    __shared__ __align__(16) unsigned char ldsA[TB];   // t_r tile  [64 rows][128] bf16
    __shared__ __align__(16) unsigned char ldsW[TB];   // W tile    [64 dims][128] bf16
    __shared__ float p1s[BR];
    __shared__ float p2s[BR][2];

    const int t    = threadIdx.x;
    const int base = blockIdx.x * BR;
    const int lane = t & 63;
    const int w    = t >> 6;
    const int rt   = w & 3;          // row-tile
    const int dh   = w >> 2;         // dim-half (0: dims 0..31, 1: dims 32..63)
    const int r16  = lane & 15;
    const int kg   = lane >> 4;

    // register-staged chunk (T14 async-stage split: load early, ds_write late)
    u32x4  rA16[2], rW16[2];
    float4 rA32[4], rW32[4];

    auto LOADS = [&](int n) {
        if constexpr (!FP32) {
            #pragma unroll
            for (int it = 0; it < 2; ++it) {           // A: 1024 x 16B
                const int lid = it * 512 + t;
                const int seg = lid >> 3, ln = lid & 7;
                const int row = seg >> 1, half = seg & 1;
                const int idx = half ? ntail[(size_t)(base + row) * NNB + n]
                                     : nrel [(size_t)(base + row) * NNB + n];
                const unsigned short* tbl = (const unsigned short*)(half ? eemb_ : remb_);
                rA16[it] = *(const u32x4*)(tbl + (size_t)idx * DIM + ln * 8);
            }
            #pragma unroll
            for (int it = 0; it < 2; ++it) {           // W: 1024 x 16B
                const int lid = it * 512 + t;
                const int d = lid >> 4, ln = lid & 15;
                rW16[it] = *(const u32x4*)((const unsigned short*)W_
                              + (size_t)d * INDIM + (size_t)n * KC + ln * 8);
            }
        } else {
            #pragma unroll
            for (int it = 0; it < 4; ++it) {           // A: 2048 x float4
                const int lid = it * 512 + t;
                const int seg = lid >> 4, ln = lid & 15;
                const int row = seg >> 1, half = seg & 1;
                const int idx = half ? ntail[(size_t)(base + row) * NNB + n]
                                     : nrel [(size_t)(base + row) * NNB + n];
                const float* tbl = (const float*)(half ? eemb_ : remb_);
                rA32[it] = ((const float4*)(tbl + (size_t)idx * DIM))[ln];
            }
            #pragma unroll
            for (int it = 0; it < 4; ++it) {           // W: 2048 x float4
                const int lid = it * 512 + t;
                const int d = lid >> 5, ln = lid & 31;
                rW32[it] = *(const float4*)((const float*)W_
                              + (size_t)d * INDIM + (size_t)n * KC + ln * 4);
            }
        }
    };

    auto split4 = [](const float4 v, u16x4& h, u16x4& l) {
        const float xs[4] = { v.x, v.y, v.z, v.w };
        #pragma unroll
        for (int j = 0; j < 4; ++j) {
            union { float f; unsigned u; } a, b, c;
            a.f = xs[j];
            const unsigned short hh = (unsigned short)(a.u >> 16);  // truncate -> hi
            b.u = ((unsigned)hh) << 16;
            c.f = xs[j] - b.f;                                      // exact remainder
            h[j] = hh;
            l[j] = (unsigned short)(c.u >> 16);
        }
    };

    auto WRITE = [&]() {
        if constexpr (!FP32) {
            #pragma unroll
            for (int it = 0; it < 2; ++it) {
                const int lid = it * 512 + t;
                const int seg = lid >> 3, ln = lid & 7;
                const int row = seg >> 1, half = seg & 1;
                const int byte = row * 256 + ((half * 128 + ln * 16) ^ ((row & 7) << 4));
                *(u32x4*)&ldsA[byte] = rA16[it];
            }
            #pragma unroll
            for (int it = 0; it < 2; ++it) {
                const int lid = it * 512 + t;
                const int d = lid >> 4, ln = lid & 15;
                const int byte = d * 256 + ((ln * 16) ^ ((d & 7) << 4));
                *(u32x4*)&ldsW[byte] = rW16[it];
            }
        } else {
            #pragma unroll
            for (int it = 0; it < 4; ++it) {
                const int lid = it * 512 + t;
                const int seg = lid >> 4, ln = lid & 15;
                const int row = seg >> 1, half = seg & 1;
                u16x4 h, l; split4(rA32[it], h, l);
                const int byte = row * 256 + ((half * 128 + ln * 8) ^ ((row & 7) << 4));
                *(u16x4*)&ldsA[byte]      = h;
                *(u16x4*)&ldsA[LO + byte] = l;
            }
            #pragma unroll
            for (int it = 0; it < 4; ++it) {
                const int lid = it * 512 + t;
                const int d = lid >> 5, ln = lid & 31;
                u16x4 h, l; split4(rW32[it], h, l);
                const int byte = d * 256 + ((ln * 8) ^ ((d & 7) << 4));
                *(u16x4*)&ldsW[byte]      = h;
                *(u16x4*)&ldsW[LO + byte] = l;
            }
        }
    };

    f32x4 acc0 = {0.f, 0.f, 0.f, 0.f};
    f32x4 acc1 = {0.f, 0.f, 0.f, 0.f};

    LOADS(0);
    WRITE();
    __syncthreads();

    for (int n = 0; n < NNB; ++n) {
        const bool more = (n + 1 < NNB);
        if (more) LOADS(n + 1);            // gathers in flight under MFMA phase

        #pragma unroll
        for (int kk = 0; kk < 4; ++kk) {   // K = 128 per chunk, 32 per MFMA
            const int cb  = (kk * 64 + kg * 16) ^ ((r16 & 7) << 4);
            const int ra  = (rt * 16 + r16) * 256 + cb;
            const int rb0 = (dh * 32 + r16) * 256 + cb;
            const int rb1 = rb0 + 16 * 256;
            if constexpr (!FP32) {
                const s16x8 a  = *(const s16x8*)&ldsA[ra];
                const s16x8 b0 = *(const s16x8*)&ldsW[rb0];
                const s16x8 b1 = *(const s16x8*)&ldsW[rb1];
                acc0 = __builtin_amdgcn_mfma_f32_16x16x32_bf16(a, b0, acc0, 0, 0, 0);
                acc1 = __builtin_amdgcn_mfma_f32_16x16x32_bf16(a, b1, acc1, 0, 0, 0);
            } else {
                const s16x8 ah  = *(const s16x8*)&ldsA[ra];
                const s16x8 al  = *(const s16x8*)&ldsA[LO + ra];
                const s16x8 bh0 = *(const s16x8*)&ldsW[rb0];
                const s16x8 bl0 = *(const s16x8*)&ldsW[LO + rb0];
                const s16x8 bh1 = *(const s16x8*)&ldsW[rb1];
                const s16x8 bl1 = *(const s16x8*)&ldsW[LO + rb1];
                acc0 = __builtin_amdgcn_mfma_f32_16x16x32_bf16(ah, bh0, acc0, 0, 0, 0);
                acc0 = __builtin_amdgcn_mfma_f32_16x16x32_bf16(ah, bl0, acc0, 0, 0, 0);
                acc0 = __builtin_amdgcn_mfma_f32_16x16x32_bf16(al, bh0, acc0, 0, 0, 0);
                acc1 = __builtin_amdgcn_mfma_f32_16x16x32_bf16(ah, bh1, acc1, 0, 0, 0);
                acc1 = __builtin_amdgcn_mfma_f32_16x16x32_bf16(ah, bl1, acc1, 0, 0, 0);
                acc1 = __builtin_amdgcn_mfma_f32_16x16x32_bf16(al, bh1, acc1, 0, 0, 0);
            }
        }
        __syncthreads();                   // all waves done reading this chunk
        if (more) WRITE();                 // vmcnt-wait + ds_write next chunk
        __syncthreads();
    }

    // Epilogue. C/D layout (m89): col = lane&15, row = (lane>>4)*4 + reg.
    // Wave w holds false_logit for rows rt*16+kg*4+q, dims dh*32 + j*16 + r16.
    float part1[4] = {0.f, 0.f, 0.f, 0.f};
    float part2[4] = {0.f, 0.f, 0.f, 0.f};
    #pragma unroll
    for (int q = 0; q < 4; ++q) {
        const int r   = rt * 16 + kg * 4 + q;
        const int row = base + r;
        const int uid = users[row];
        #pragma unroll
        for (int j = 0; j < 2; ++j) {
            const int d  = (dh * 2 + j) * 16 + r16;
            const float fl = (j == 0 ? acc0[q] : acc1[q]) + ldT<FP32>(b_, d);
            const float fi = 1.f / (1.f + expf(-fl));             // false_item[d]
            const float uv = ldT<FP32>(uemb_, (size_t)uid * DIM + d);
            part2[q] += uv * fi;
        }
        if (dh == 0) {                      // dh0 waves compute predict = u . i
            const int iid = items[row];
            #pragma unroll
            for (int jj = 0; jj < 4; ++jj) {
                const int d = jj * 16 + r16;
                const float uv = ldT<FP32>(uemb_, (size_t)uid * DIM + d);
                const float iv = ldT<FP32>(eemb_, (size_t)iid * DIM + d);
                part1[q] += uv * iv;
            }
        }
    }
    #pragma unroll
    for (int m = 1; m < 16; m <<= 1) {      // reduce across the 16-lane dim groups
        #pragma unroll
        for (int q = 0; q < 4; ++q) {
            part2[q] += __shfl_xor(part2[q], m, 64);
            part1[q] += __shfl_xor(part1[q], m, 64);
        }
    }
    if (r16 == 0) {
        #pragma unroll
        for (int q = 0; q < 4; ++q) {
            const int r = rt * 16 + kg * 4 + q;
            p2s[r][dh] = part2[q];
            if (dh == 0) p1s[r] = part1[q];
        }
    }
    __syncthreads();

    if (t < BR) {                           // wave 0: one BCE term per row
        const int r = t, row = base + r;
        const float p1 = p1s[r];
        const float p2 = p2s[r][0] + p2s[r][1];
        const float y  = ldT<FP32>(label_, row);
        const float pa = 1.f / (1.f + expf(-p1));
        const float pb = 1.f / (1.f + expf(-p2));
        float term =
              y * fmaxf(logf(pa), -100.f) + (1.f - y) * fmaxf(log1pf(-pa), -100.f)
            + y * fmaxf(logf(pb), -100.f) + (1.f - y) * fmaxf(log1pf(-pb), -100.f);
        #pragma unroll
        for (int m = 1; m < 64; m <<= 1) term += __shfl_xor(term, m, 64);
        if (r == 0) atomicAdd(acc, (double)term);   // 1 atomic per block (256 total)
    }
}

__global__ void kgnn_fin(const double* __restrict__ acc,
                         const int* __restrict__ flag, void* __restrict__ out,
                         const int mode) {
    if (threadIdx.x == 0 && blockIdx.x == 0) {
        const int m = (mode < 0) ? *flag : mode;
        const float loss = (float)(-(*acc) / (double)BATCH);
        if (m) ((float*)out)[0] = loss;
        else   ((__hip_bfloat16*)out)[0] = __float2bfloat16(loss);
    }
}

extern "C" void kernel_launch(void* const* d_in, const int* in_sizes, int n_in,
                              void* d_out, int out_size, void* d_ws, size_t ws_size,
                              hipStream_t stream) {
    const int* users = (const int*)d_in[0];
    const int* items = (const int*)d_in[1];
    const void* label = d_in[2];
    const int* nrel  = (const int*)d_in[3];
    const int* ntail = (const int*)d_in[4];
    const void* uemb = d_in[5];
    const void* eemb = d_in[6];
    const void* remb = d_in[7];
    const void* genW = d_in[8];
    const void* genb = d_in[9];

    double* acc = (double*)d_ws;
    int* flag   = (int*)((char*)d_ws + 8);
    hipMemsetAsync(d_ws, 0, 16, stream);

    // Host-side dtype resolution: out_size (2B bf16 / 4B fp32 scalar) must agree
    // with user_emb bytes (500000*64*{2,4}). Decisive -> single forced launch;
    // anything unexpected -> previous probe + both-variants fallback.
    const bool f32sz  = (out_size == 4) && (in_sizes[5] == 128000000);
    const bool bf16sz = (out_size == 2) && (in_sizes[5] == 64000000);
    const int grid = BATCH / BR;   // 256 blocks

    if (f32sz) {
        kgnn_mfma<true><<<grid, 512, 0, stream>>>(
            users, items, label, nrel, ntail, uemb, eemb, remb, genW, genb, acc, flag, 1);
        kgnn_fin<<<1, 64, 0, stream>>>(acc, flag, d_out, 1);
    } else if (bf16sz) {
        kgnn_mfma<false><<<grid, 512, 0, stream>>>(
            users, items, label, nrel, ntail, uemb, eemb, remb, genW, genb, acc, flag, 1);
        kgnn_fin<<<1, 64, 0, stream>>>(acc, flag, d_out, 0);
    } else {
        kgnn_probe<<<1, 64, 0, stream>>>((const unsigned int*)label, flag);
        kgnn_mfma<false><<<grid, 512, 0, stream>>>(
            users, items, label, nrel, ntail, uemb, eemb, remb, genW, genb, acc, flag, -1);
        kgnn_mfma<true><<<grid, 512, 0, stream>>>(
            users, items, label, nrel, ntail, uemb, eemb, remb, genW, genb, acc, flag, -1);
        kgnn_fin<<<1, 64, 0, stream>>>(acc, flag, d_out, -1);
    }
}